// Round 9
// baseline (158.287 us; speedup 1.0000x reference)
//
#include <hip/hip_runtime.h>
#include <cstddef>
#include <cstdint>

#define NTOK 4096
#define NB_  8

// 0.25 (=1/sqrt(Cq)) * log2(e): folded into q so flash can use raw exp2.
#define QSCALE 0.36067376022224085f

typedef float f32x4  __attribute__((ext_vector_type(4)));
typedef float f32x16 __attribute__((ext_vector_type(16)));
typedef short s16x8  __attribute__((ext_vector_type(8)));

#if __has_builtin(__builtin_amdgcn_exp2f)
#define EXP2F(x) __builtin_amdgcn_exp2f(x)
#else
#define EXP2F(x) exp2f(x)
#endif

static __device__ __forceinline__ unsigned short f2bf(float f) {
    unsigned u = __float_as_uint(f);
    unsigned r = (u + 0x7FFFu + ((u >> 16) & 1u)) >> 16;
    return (unsigned short)r;
}

// 2 f32 -> packed bf16 pair (low half = a), RNE.
static __device__ __forceinline__ unsigned cvtpkbf(float a, float b) {
    unsigned r;
    asm("v_cvt_pk_bf16_f32 %0, %1, %2" : "=v"(r) : "v"(a), "v"(b));
    return r;
}

// v_permlane32_swap_b32: ret.x = [a(lanes0-31) | b(lanes0-31)],
//                        ret.y = [a(lanes32-63) | b(lanes32-63)].
static __device__ __forceinline__ uint2 plswap32(unsigned a, unsigned b) {
#if __has_builtin(__builtin_amdgcn_permlane32_swap)
    auto r = __builtin_amdgcn_permlane32_swap((int)a, (int)b, false, false);
    return make_uint2((unsigned)r[0], (unsigned)r[1]);
#else
    const int xa = (((int)threadIdx.x & 63) ^ 32) << 2;
    const unsigned pa = (unsigned)__builtin_amdgcn_ds_bpermute(xa, (int)a);
    const unsigned pb = (unsigned)__builtin_amdgcn_ds_bpermute(xa, (int)b);
    const bool hi = (threadIdx.x & 32) != 0;
    return make_uint2(hi ? pb : a, hi ? b : pa);
#endif
}

// lane^16 exchange (within each 32-lane half): ds_swizzle BitMode xor=16
static __device__ __forceinline__ unsigned swz16(unsigned v) {
    return (unsigned)__builtin_amdgcn_ds_swizzle((int)v, 0x401F);
}

// async global(16B/lane) -> LDS(base + lane*16), wave-level
static __device__ __forceinline__ void gload16(const void* g, void* l) {
    __builtin_amdgcn_global_load_lds(
        (const __attribute__((address_space(1))) unsigned int*)g,
        (__attribute__((address_space(3))) unsigned int*)l, 16, 0, 0);
}

// ---------------- P0: weights fp32 -> bf16 ----------------
__global__ __launch_bounds__(256) void wcvt_kernel(
    const float* __restrict__ Wq, const float* __restrict__ Wk, const float* __restrict__ Wv,
    unsigned short* __restrict__ wvb, unsigned short* __restrict__ wqb,
    unsigned short* __restrict__ wkb)
{
    int i = blockIdx.x * 256 + threadIdx.x;  // 0..20479
    if (i < 16384)      wvb[i]         = f2bf(Wv[i]);
    else if (i < 18432) wqb[i - 16384] = f2bf(Wq[i - 16384]);
    else                wkb[i - 18432] = f2bf(Wk[i - 18432]);
}

// ---------------- P1: fused transpose + projections (channel-split) ----------
// Grid 1024 blocks: b = blk & 7 (XCD-pinned), vh = (blk>>3)&1 (V channel half),
// n-tile = blk>>4 (64 tokens). The vh pair of a tile shares the staged x-tile
// through same-XCD L2 (blocks differ by 8 -> same XCD, dispatched adjacently).
// r8 diagnosis: proj suspected latency-bound at 2 blocks/CU; this doubles
// block-level parallelism (4/CU) and halves each block's serial V chain.
// vh=0: V channels 0..63 + Q/K. vh=1: V channels 64..127.
__global__ __launch_bounds__(256) void proj_kernel(
    const float* __restrict__ x,
    const unsigned short* __restrict__ wvb, const unsigned short* __restrict__ wqb,
    const unsigned short* __restrict__ wkb,
    const float* __restrict__ bq, const float* __restrict__ bk, const float* __restrict__ bv,
    unsigned short* __restrict__ qb, unsigned short* __restrict__ kb,
    unsigned short* __restrict__ vt)
{
    __shared__ float lt[128][68];   // [c][n0..63], padded rows (16B-aligned stride)
    const int t = threadIdx.x;
    const int w = t >> 6, lane = t & 63;
    const int c16 = lane & 15, g16 = lane >> 4;
    const int b  = blockIdx.x & 7;
    const int vh = (blockIdx.x >> 3) & 1;
    const int n0 = (blockIdx.x >> 4) * 64;

    // stage x tile: 128 rows x 64 floats
    {
        const int n4 = t & 15;
#pragma unroll
        for (int pass = 0; pass < 8; ++pass) {
            const int c = (t >> 4) + 16 * pass;
            const float4 val = ((const float4*)(x + ((size_t)b * 128 + c) * NTOK + n0))[n4];
            *(float4*)&lt[c][n4 * 4] = val;
        }
    }
    __syncthreads();

    // xf fragments for this wave's 16 tokens (token = n0 + 16w + c16)
    const int nl = 16 * w + c16;
    s16x8 xf[4];
#pragma unroll
    for (int kc = 0; kc < 4; ++kc) {
        unsigned rr[8];
#pragma unroll
        for (int i = 0; i < 8; ++i) {
            const unsigned u = __float_as_uint(lt[32 * kc + 8 * g16 + i][nl]);
            rr[i] = u + 0x7FFFu + ((u >> 16) & 1u);
        }
        union { s16x8 v; unsigned u[4]; } cvt;
#pragma unroll
        for (int d = 0; d < 4; ++d)
            cvt.u[d] = __builtin_amdgcn_perm(rr[2 * d + 1], rr[2 * d], 0x07060302u);
        xf[kc] = cvt.v;
    }

    // ---- V = Wv * X for this block's channel half (fragment-major, dense 16B stores) ----
    unsigned short* vwp16 = vt + (size_t)b * (NTOK * 128) +
                            (size_t)(((n0 >> 6) * 8) + 2 * w + (g16 >> 1)) * 1024;
    const bool oddg = (g16 & 1) != 0;
#pragma unroll
    for (int mp = 0; mp < 2; ++mp) {
        const int mpa = 2 * vh + mp;
        f32x4 accA = {0.f, 0.f, 0.f, 0.f}, accB = {0.f, 0.f, 0.f, 0.f};
#pragma unroll
        for (int kc = 0; kc < 4; ++kc) {
            const s16x8 wfA = *(const s16x8*)(wvb + (size_t)(32 * mpa      + c16) * 128 + 32 * kc + 8 * g16);
            const s16x8 wfB = *(const s16x8*)(wvb + (size_t)(32 * mpa + 16 + c16) * 128 + 32 * kc + 8 * g16);
            accA = __builtin_amdgcn_mfma_f32_16x16x32_bf16(xf[kc], wfA, accA, 0, 0, 0);
            accB = __builtin_amdgcn_mfma_f32_16x16x32_bf16(xf[kc], wfB, accB, 0, 0, 0);
        }
        const float bvA = bv[32 * mpa + c16], bvB = bv[32 * mpa + 16 + c16];
        uint2 A, B;
        A.x = cvtpkbf(accA[0] + bvA, accA[1] + bvA);
        A.y = cvtpkbf(accA[2] + bvA, accA[3] + bvA);
        B.x = cvtpkbf(accB[0] + bvB, accB[1] + bvB);
        B.y = cvtpkbf(accB[2] + bvB, accB[3] + bvB);
        const unsigned s0 = swz16(oddg ? A.x : B.x);
        const unsigned s1 = swz16(oddg ? A.y : B.y);
        uint4 W;
        W.x = oddg ? s0 : A.x;
        W.y = oddg ? s1 : A.y;
        W.z = oddg ? B.x : s0;
        W.w = oddg ? B.y : s1;
        const int crow = 32 * mpa + (oddg ? 16 : 0) + c16;
        *(uint4*)(vwp16 + (size_t)crow * 8) = W;
    }

    // ---- Q, K (vh==0 blocks only; block-uniform branch) ----
    if (vh == 0) {
        f32x4 aq = {0.f, 0.f, 0.f, 0.f}, ak = {0.f, 0.f, 0.f, 0.f};
#pragma unroll
        for (int kc = 0; kc < 4; ++kc) {
            const s16x8 wqf = *(const s16x8*)(wqb + (size_t)c16 * 128 + 32 * kc + 8 * g16);
            const s16x8 wkf = *(const s16x8*)(wkb + (size_t)c16 * 128 + 32 * kc + 8 * g16);
            aq = __builtin_amdgcn_mfma_f32_16x16x32_bf16(wqf, xf[kc], aq, 0, 0, 0);
            ak = __builtin_amdgcn_mfma_f32_16x16x32_bf16(wkf, xf[kc], ak, 0, 0, 0);
        }
        const float4 bq4 = *(const float4*)(bq + 4 * g16);
        const float4 bk4 = *(const float4*)(bk + 4 * g16);
        const int n = n0 + 16 * w + c16;
        uint2 pq, pkk;
        pq.x  = cvtpkbf(QSCALE * (aq[0] + bq4.x), QSCALE * (aq[1] + bq4.y));
        pq.y  = cvtpkbf(QSCALE * (aq[2] + bq4.z), QSCALE * (aq[3] + bq4.w));
        pkk.x = cvtpkbf(ak[0] + bk4.x, ak[1] + bk4.y);
        pkk.y = cvtpkbf(ak[2] + bk4.z, ak[3] + bk4.w);
        *(uint2*)(qb + ((size_t)b * NTOK + n) * 16 + 4 * g16) = pq;
        *(uint2*)(kb + ((size_t)b * NTOK + n) * 16 + 4 * g16) = pkk;
    }
}

// ---------------- P2: flash attention, register-V, j-split waves --------------
// Grid 1024 blocks (4/CU): b = blk & 7 (XCD-pinned batch), m-tile = blk>>3
// (32 q rows). 4 waves = (jw 0..1) x (cv 0..1): wave owns j-half jw and output
// channel pair ct in {2cv, 2cv+1}.
//
// r8 diagnosis: LDS path (~1536 cyc/CU/tile: 64 vf reads + pf exchange + 18KB
// staging) + 2 waves/SIMD was the wall; same-occupancy rescheduling moved
// nothing twice. This version: V fragments load straight from global into
// registers (the 16 fragments of a tile map 1:1 onto the 4 waves - each block
// reads each V tile exactly once, L2-resident); softmax computed per-wave for
// its own j-half (no pf LDS exchange, no pipelining); LDS only stages 2KB K
// tiles. O partials combined across jw once at the end. ~110 VGPR under
// launch_bounds(256,2) -> ~4 waves/SIMD, 2x occupancy.
__global__ __launch_bounds__(256, 2) void flash_kernel(
    const unsigned short* __restrict__ qb, const unsigned short* __restrict__ kb,
    const unsigned short* __restrict__ vt, const float* __restrict__ x,
    const float* __restrict__ gamma, float* __restrict__ out)
{
    // sK 3*2048 @0; cmb float[32][128] @6144 (16KB); lb 4*32 floats @22528
    __shared__ __align__(16) unsigned char smem[23040];

    const int t = threadIdx.x;
    const int w = t >> 6, lane = t & 63;
    const int m31 = lane & 31, h = lane >> 5;
    const int cv = w & 1, jw = w >> 1;
    const int b  = blockIdx.x & 7;
    const int m0 = (blockIdx.x >> 3) * 32;

    const unsigned short* vtile0 = vt + (size_t)b * (NTOK * 128);  // 16KB per jt tile
    const unsigned short* ktile0 = kb + (size_t)b * (NTOK * 16);   // 2KB per jt tile

    // Q B-frag: B[k=ch 8h+e][n=m31]; scale (incl. log2e) pre-folded into qb.
    const s16x8 qf = *(const s16x8*)(qb + ((size_t)b * NTOK + m0 + m31) * 16 + 8 * h);

    f32x16 O[2];   // 32 loop-carried acc regs (ct = 2cv + ci), partial over half jw
#pragma unroll
    for (int ci = 0; ci < 2; ++ci)
#pragma unroll
        for (int r = 0; r < 16; ++r) O[ci][r] = 0.f;
    float la0 = 0.f, la1 = 0.f, la2 = 0.f, la3 = 0.f;

#define STAGE_K(d, jt_) do {                                                        \
        if (w < 2) {                                                                \
            const unsigned short* ks_ = ktile0 + (size_t)(jt_) * 1024 + w * 512 + lane * 8; \
            gload16(ks_, smem + (d) * 2048 + w * 1024);                             \
        }                                                                           \
    } while (0)

    STAGE_K(0, 0);
    STAGE_K(1, 1);
    __syncthreads();   // K tiles 0,1 resident

    for (int jt = 0; jt < 64; ++jt) {
        // V fragments for own half jw, own ct pair: 4 x 16B/lane from global
        // (each covers a contiguous 1KB region per wave -> perfectly coalesced)
        const unsigned short* vj = vtile0 + (size_t)jt * 8192 + (2 * jw) * 2048 +
                                   h * 1024 + (2 * cv) * 256 + m31 * 8;
        s16x8 vf[2][2];
#pragma unroll
        for (int sl = 0; sl < 2; ++sl)
#pragma unroll
            for (int ci = 0; ci < 2; ++ci)
                vf[sl][ci] = *(const s16x8*)(vj + sl * 2048 + ci * 256);

        if (jt < 62) STAGE_K((jt + 2) % 3, jt + 2);

        // K A-frag for own half: rows j-local = 32jw + m31, from buffer jt%3
        const s16x8 kf = *(const s16x8*)((const unsigned short*)(smem + (jt % 3) * 2048) +
                                         (size_t)(32 * jw + m31) * 16 + 8 * h);

        // scores: S^T (D[j][m]) for own 32-j half
        f32x16 sd;
#pragma unroll
        for (int r = 0; r < 16; ++r) sd[r] = 0.f;
        sd = __builtin_amdgcn_mfma_f32_32x32x16_bf16(kf, qf, sd, 0, 0, 0);

        // softmax numerator: exp2 (scale folded), pack quads to bf16 pairs
        uint2 pk[4];
#pragma unroll
        for (int q = 0; q < 4; ++q) {
            const float e0 = EXP2F(sd[4 * q + 0]);
            const float e1 = EXP2F(sd[4 * q + 1]);
            const float e2 = EXP2F(sd[4 * q + 2]);
            const float e3 = EXP2F(sd[4 * q + 3]);
            la0 += e0; la1 += e1; la2 += e2; la3 += e3;
            pk[q].x = cvtpkbf(e0, e1);
            pk[q].y = cvtpkbf(e2, e3);
        }

        // register-only C->B transform via permlane32_swap (r2-verified)
        s16x8 pf[2];
#pragma unroll
        for (int s1 = 0; s1 < 2; ++s1) {
            const uint2 rx = plswap32(pk[2 * s1].x, pk[2 * s1 + 1].x);
            const uint2 ry = plswap32(pk[2 * s1].y, pk[2 * s1 + 1].y);
            union { s16x8 v; unsigned u[4]; } A;
            A.u[0] = rx.x; A.u[1] = ry.x; A.u[2] = rx.y; A.u[3] = ry.y;
            pf[s1] = A.v;
        }

        // PV own half only: O[ci] += V^T * P^T (4 MFMAs)
#pragma unroll
        for (int sl = 0; sl < 2; ++sl)
#pragma unroll
            for (int ci = 0; ci < 2; ++ci)
                O[ci] = __builtin_amdgcn_mfma_f32_32x32x16_bf16(vf[sl][ci], pf[sl], O[ci], 0, 0, 0);

        __syncthreads();   // K buffer rotation safety (also drains gload vmcnt)
    }
#undef STAGE_K

    // own-half l (h-lanes hold disjoint j subsets of the half)
    float l_acc = (la0 + la1) + (la2 + la3);
    l_acc += __shfl_xor(l_acc, 32);

    // l across jw partner (w^2). (cv partners duplicate softmax -> same la.)
    float* lb  = (float*)(smem + 22528);
    float* cmb = (float*)(smem + 6144);    // [32][128] floats
    if (lane < 32) lb[w * 32 + m31] = l_acc;
    __syncthreads();
    const float l_tot = l_acc + lb[(w ^ 2) * 32 + m31];

    // O combine across jw: jw=1 publishes, jw=0 adds and stores.
    if (jw == 1) {
#pragma unroll
        for (int ci = 0; ci < 2; ++ci)
#pragma unroll
            for (int r = 0; r < 16; ++r)
                cmb[(ci * 16 + r) * 128 + cv * 64 + lane] = O[ci][r];
    }
    __syncthreads();
    if (jw == 0) {
        const float linv = 1.f / l_tot;
        const float g = gamma[0];
#pragma unroll
        for (int ci = 0; ci < 2; ++ci) {
            const int ct = 2 * cv + ci;
#pragma unroll
            for (int r = 0; r < 16; ++r) {
                const float ov = O[ci][r] + cmb[(ci * 16 + r) * 128 + cv * 64 + lane];
                const int c = 32 * ct + (r & 3) + 8 * (r >> 2) + 4 * h;
                const size_t idx = ((size_t)b * 128 + c) * NTOK + m0 + m31;
                out[idx] = fmaf(g, ov * linv, x[idx]);
            }
        }
    }
}

extern "C" void kernel_launch(void* const* d_in, const int* in_sizes, int n_in,
                              void* d_out, int out_size, void* d_ws, size_t ws_size,
                              hipStream_t stream)
{
    const float* x     = (const float*)d_in[0];
    const float* Wq    = (const float*)d_in[1];
    const float* bq    = (const float*)d_in[2];
    const float* Wk    = (const float*)d_in[3];
    const float* bk    = (const float*)d_in[4];
    const float* Wv    = (const float*)d_in[5];
    const float* bv    = (const float*)d_in[6];
    const float* gamma = (const float*)d_in[7];
    float* out = (float*)d_out;

    // workspace (bf16 elements)
    unsigned short* qb  = (unsigned short*)d_ws;                 // 8*4096*16
    unsigned short* kb  = qb  + (size_t)NB_ * NTOK * 16;
    unsigned short* vt  = kb  + (size_t)NB_ * NTOK * 16;         // 8*128*4096 (fragment-major)
    unsigned short* wvb = vt  + (size_t)NB_ * 128 * NTOK;        // 128*128
    unsigned short* wqb = wvb + 16384;                           // 16*128
    unsigned short* wkb = wqb + 2048;

    wcvt_kernel<<<80, 256, 0, stream>>>(Wq, Wk, Wv, wvb, wqb, wkb);
    proj_kernel<<<1024, 256, 0, stream>>>(x, wvb, wqb, wkb, bq, bk, bv, qb, kb, vt);
    flash_kernel<<<1024, 256, 0, stream>>>(qb, kb, vt, x, gamma, out);
}